// Round 1
// baseline (458.307 us; speedup 1.0000x reference)
//
#include <hip/hip_runtime.h>
#include <hip/hip_fp16.h>

#define LDIM 256
#define NDIM 256
#define DZC  128
#define HN   4
#define DHD  32
#define DCC  128
#define MROWS (LDIM*NDIM)

typedef unsigned int u32;

__device__ inline u32 pack2(float a, float b){
  __half2 h = __floats2half2_rn(a, b);
  return *reinterpret_cast<u32*>(&h);
}
__device__ inline float2 up2(u32 u){
  __half2 h = *reinterpret_cast<__half2*>(&u);
  return __half22float2(h);
}

// ---------------- K1: LayerNorm + Q/K/V/Gate projections ----------------
// block = 128 rows, 256 threads. z_ln staged in LDS (stride 129: conflict-free
// broadcast reads in GEMM loop, 2-way-free writes). Each thread: 8 rows x 8 cols.
__global__ __launch_bounds__(256) void k1_ln_qkvg(
    const float* __restrict__ z, const float* __restrict__ lng, const float* __restrict__ lnb,
    const float* __restrict__ Wq, const float* __restrict__ bq,
    const float* __restrict__ Wk, const float* __restrict__ bk,
    const float* __restrict__ Wv, const float* __restrict__ bv,
    const float* __restrict__ Wg, const float* __restrict__ bg,
    __half* __restrict__ qb, __half* __restrict__ kbuf,
    __half* __restrict__ vbuf, __half* __restrict__ gateb)
{
  __shared__ float zl[128*129];
  const int t = threadIdx.x;
  const int row0 = blockIdx.x * 128;

  { // LayerNorm: 2 threads per row, 64 elems each
    const int r = t >> 1, hf = t & 1;
    const float* zr = z + (size_t)(row0 + r) * DZC + hf*64;
    float vals[64];
    float s = 0.f, sq = 0.f;
    #pragma unroll
    for (int i = 0; i < 16; ++i) {
      float4 v4 = reinterpret_cast<const float4*>(zr)[i];
      vals[i*4+0]=v4.x; vals[i*4+1]=v4.y; vals[i*4+2]=v4.z; vals[i*4+3]=v4.w;
      s  += v4.x+v4.y+v4.z+v4.w;
      sq += v4.x*v4.x + v4.y*v4.y + v4.z*v4.z + v4.w*v4.w;
    }
    s  += __shfl_xor(s, 1);
    sq += __shfl_xor(sq, 1);
    const float mu  = s * (1.f/DZC);
    const float var = sq * (1.f/DZC) - mu*mu;
    const float rstd = rsqrtf(var + 1e-5f);
    const float* gg = lng + hf*64;
    const float* bb = lnb + hf*64;
    float* dst = &zl[r*129 + hf*64];
    #pragma unroll
    for (int i = 0; i < 64; ++i) dst[i] = (vals[i]-mu)*rstd*gg[i] + bb[i];
  }
  __syncthreads();

  const int cg = t & 15, rg = t >> 4;   // 16 col-groups x 16 row-groups
  const float* Ws[4]  = {Wq, Wk, Wv, Wg};
  const float* bs[4]  = {bq, bk, bv, bg};
  __half* outs[3] = {qb, kbuf, vbuf};
  #pragma unroll
  for (int p = 0; p < 4; ++p) {
    float bias[8];
    #pragma unroll
    for (int cc=0;cc<8;++cc) bias[cc] = bs[p][cg*8+cc];
    float acc[8][8];
    #pragma unroll
    for (int rr=0;rr<8;++rr)
      #pragma unroll
      for (int cc=0;cc<8;++cc) acc[rr][cc] = bias[cc];

    const float* W = Ws[p];
    for (int c = 0; c < DZC; ++c) {
      const float4 w0 = *reinterpret_cast<const float4*>(W + c*DCC + cg*8);
      const float4 w1 = *reinterpret_cast<const float4*>(W + c*DCC + cg*8 + 4);
      const float wv[8] = {w0.x,w0.y,w0.z,w0.w,w1.x,w1.y,w1.z,w1.w};
      #pragma unroll
      for (int rr=0;rr<8;++rr){
        const float zv = zl[(rg*8+rr)*129 + c];
        #pragma unroll
        for (int cc=0;cc<8;++cc) acc[rr][cc] += zv * wv[cc];
      }
    }

    if (p < 3) {
      __half* ob = outs[p];
      const int hh = cg >> 2, dh0 = (cg & 3) * 8;
      #pragma unroll
      for (int rr=0;rr<8;++rr){
        const int row = row0 + rg*8 + rr;
        const int l = row >> 8, i = row & 255;
        uint4 u;
        u.x = pack2(acc[rr][0], acc[rr][1]);
        u.y = pack2(acc[rr][2], acc[rr][3]);
        u.z = pack2(acc[rr][4], acc[rr][5]);
        u.w = pack2(acc[rr][6], acc[rr][7]);
        *reinterpret_cast<uint4*>(ob + ((size_t)((l*HN + hh)*NDIM + i))*DHD + dh0) = u;
      }
    } else {
      #pragma unroll
      for (int rr=0;rr<8;++rr){
        const int row = row0 + rg*8 + rr;
        float gv[8];
        #pragma unroll
        for (int cc=0;cc<8;++cc) gv[cc] = 1.f/(1.f + __expf(-acc[rr][cc]));
        uint4 u;
        u.x = pack2(gv[0],gv[1]); u.y = pack2(gv[2],gv[3]);
        u.z = pack2(gv[4],gv[5]); u.w = pack2(gv[6],gv[7]);
        *reinterpret_cast<uint4*>(gateb + (size_t)row*DCC + cg*8) = u;
      }
    }
  }
}

// ---------------- K2: fused attention per (l, h) ----------------
// block = one (l,h), 256 threads, one query row per thread. K,V staged in LDS
// as f32 (broadcast reads, conflict-free). dist staged in 8-column chunks,
// stride 9 (odd -> 2-way-free per-lane reads). No-max softmax: logits are
// tiny (|s*coef| < ~0.5), so exp(s*c)/sum is exact softmax.
__global__ __launch_bounds__(256) void k2_attn(
    const __half* __restrict__ qb, const __half* __restrict__ kbuf,
    const __half* __restrict__ vbuf, const __half* __restrict__ gateb,
    const float* __restrict__ dist, __half* __restrict__ zcom)
{
  __shared__ float kl[NDIM*DHD];   // 32KB
  __shared__ float vl[NDIM*DHD];   // 32KB
  __shared__ float dl[NDIM*9];     // 9.2KB
  const int t = threadIdx.x;
  const int bid = blockIdx.x;
  const int l = bid >> 2, h = bid & 3;
  const size_t hb = ((size_t)(l*HN + h)) * NDIM * DHD;

  { // stage K,V: f16 -> f32 LDS
    const uint4* kg = reinterpret_cast<const uint4*>(kbuf + hb);
    const uint4* vg = reinterpret_cast<const uint4*>(vbuf + hb);
    #pragma unroll
    for (int p = 0; p < 4; ++p) {
      const int g = p*256 + t;                 // uint4 granule = 8 halves
      uint4 ku = kg[g]; uint4 vu = vg[g];
      float2 a = up2(ku.x), b = up2(ku.y), c = up2(ku.z), d = up2(ku.w);
      float4* k4 = reinterpret_cast<float4*>(kl) + g*2;
      k4[0] = make_float4(a.x,a.y,b.x,b.y);
      k4[1] = make_float4(c.x,c.y,d.x,d.y);
      a = up2(vu.x); b = up2(vu.y); c = up2(vu.z); d = up2(vu.w);
      float4* v4 = reinterpret_cast<float4*>(vl) + g*2;
      v4[0] = make_float4(a.x,a.y,b.x,b.y);
      v4[1] = make_float4(c.x,c.y,d.x,d.y);
    }
  }

  float qf[DHD];
  { // q row -> regs
    const uint4* qg = reinterpret_cast<const uint4*>(qb + hb + (size_t)t*DHD);
    #pragma unroll
    for (int p = 0; p < 4; ++p) {
      uint4 u = qg[p];
      float2 f;
      f = up2(u.x); qf[p*8+0]=f.x; qf[p*8+1]=f.y;
      f = up2(u.y); qf[p*8+2]=f.x; qf[p*8+3]=f.y;
      f = up2(u.z); qf[p*8+4]=f.x; qf[p*8+5]=f.y;
      f = up2(u.w); qf[p*8+6]=f.x; qf[p*8+7]=f.y;
    }
  }

  const float scalar = 0.17677669529663687f;  // 1/sqrt(32)
  float O[DHD];
  #pragma unroll
  for (int c=0;c<DHD;++c) O[c] = 0.f;
  float rs = 0.f;
  const float* drow = dist + (size_t)l*NDIM*NDIM;

  for (int j0 = 0; j0 < NDIM; j0 += 8) {
    __syncthreads();
    #pragma unroll
    for (int p = 0; p < 2; ++p) {          // stage dist[:, j0:j0+8]
      const int g = p*256 + t;             // 512 float4 granules
      const int rr = g >> 1, c4 = (g & 1) * 4;
      const float4 d4 = *reinterpret_cast<const float4*>(drow + (size_t)rr*NDIM + j0 + c4);
      float* dd = &dl[rr*9 + c4];
      dd[0]=d4.x; dd[1]=d4.y; dd[2]=d4.z; dd[3]=d4.w;
    }
    __syncthreads();
    #pragma unroll
    for (int jj = 0; jj < 8; ++jj) {
      const int j = j0 + jj;
      const float4* kr = reinterpret_cast<const float4*>(kl + j*DHD);
      float s = 0.f;
      #pragma unroll
      for (int c4 = 0; c4 < 8; ++c4) {
        const float4 kv = kr[c4];
        s += qf[c4*4+0]*kv.x + qf[c4*4+1]*kv.y + qf[c4*4+2]*kv.z + qf[c4*4+3]*kv.w;
      }
      const float d = dl[t*9 + jj];
      const float coef = __expf(d*d*(-1.f/128.f));
      const float pw = __expf(s*scalar*coef);
      rs += pw;
      const float4* vr = reinterpret_cast<const float4*>(vl + j*DHD);
      #pragma unroll
      for (int c4 = 0; c4 < 8; ++c4) {
        const float4 vv = vr[c4];
        O[c4*4+0] += pw*vv.x; O[c4*4+1] += pw*vv.y;
        O[c4*4+2] += pw*vv.z; O[c4*4+3] += pw*vv.w;
      }
    }
  }

  // epilogue: normalize, gate, store z_com (f16)
  const float inv = 1.f/rs;
  const uint4* g4 = reinterpret_cast<const uint4*>(gateb + ((size_t)(l*NDIM + t))*DCC + h*DHD);
  uint4* z4 = reinterpret_cast<uint4*>(zcom + ((size_t)(l*NDIM + t))*DCC + h*DHD);
  #pragma unroll
  for (int p = 0; p < 4; ++p) {
    uint4 gu = g4[p];
    float2 f0 = up2(gu.x), f1 = up2(gu.y), f2 = up2(gu.z), f3 = up2(gu.w);
    uint4 u;
    u.x = pack2(O[p*8+0]*inv*f0.x, O[p*8+1]*inv*f0.y);
    u.y = pack2(O[p*8+2]*inv*f1.x, O[p*8+3]*inv*f1.y);
    u.z = pack2(O[p*8+4]*inv*f2.x, O[p*8+5]*inv*f2.y);
    u.w = pack2(O[p*8+6]*inv*f3.x, O[p*8+7]*inv*f3.y);
    z4[p] = u;
  }
}

// ---------------- K3: output projection ----------------
__global__ __launch_bounds__(256) void k3_out(
    const __half* __restrict__ zcom, const float* __restrict__ Wo,
    const float* __restrict__ bo, float* __restrict__ out)
{
  __shared__ float zl[128*129];
  const int t = threadIdx.x;
  const int row0 = blockIdx.x * 128;
  {
    const int r = t >> 1, hf = t & 1;
    const uint4* zr = reinterpret_cast<const uint4*>(zcom + (size_t)(row0 + r)*DCC + hf*64);
    float* dst = &zl[r*129 + hf*64];
    #pragma unroll
    for (int i = 0; i < 8; ++i) {
      uint4 u = zr[i];
      float2 f0 = up2(u.x), f1 = up2(u.y), f2 = up2(u.z), f3 = up2(u.w);
      dst[i*8+0]=f0.x; dst[i*8+1]=f0.y; dst[i*8+2]=f1.x; dst[i*8+3]=f1.y;
      dst[i*8+4]=f2.x; dst[i*8+5]=f2.y; dst[i*8+6]=f3.x; dst[i*8+7]=f3.y;
    }
  }
  __syncthreads();
  const int cg = t & 15, rg = t >> 4;
  float bias[8];
  #pragma unroll
  for (int cc=0;cc<8;++cc) bias[cc] = bo[cg*8+cc];
  float acc[8][8];
  #pragma unroll
  for (int rr=0;rr<8;++rr)
    #pragma unroll
    for (int cc=0;cc<8;++cc) acc[rr][cc] = bias[cc];
  for (int c = 0; c < DCC; ++c) {
    const float4 w0 = *reinterpret_cast<const float4*>(Wo + c*DZC + cg*8);
    const float4 w1 = *reinterpret_cast<const float4*>(Wo + c*DZC + cg*8 + 4);
    const float wv[8] = {w0.x,w0.y,w0.z,w0.w,w1.x,w1.y,w1.z,w1.w};
    #pragma unroll
    for (int rr=0;rr<8;++rr){
      const float zv = zl[(rg*8+rr)*129 + c];
      #pragma unroll
      for (int cc=0;cc<8;++cc) acc[rr][cc] += zv*wv[cc];
    }
  }
  #pragma unroll
  for (int rr=0;rr<8;++rr){
    float* orow = out + (size_t)(row0 + rg*8 + rr)*DZC + cg*8;
    reinterpret_cast<float4*>(orow)[0] = make_float4(acc[rr][0],acc[rr][1],acc[rr][2],acc[rr][3]);
    reinterpret_cast<float4*>(orow)[1] = make_float4(acc[rr][4],acc[rr][5],acc[rr][6],acc[rr][7]);
  }
}

extern "C" void kernel_launch(void* const* d_in, const int* in_sizes, int n_in,
                              void* d_out, int out_size, void* d_ws, size_t ws_size,
                              hipStream_t stream) {
  const float* z    = (const float*)d_in[0];
  const float* dist = (const float*)d_in[1];
  const float* lng  = (const float*)d_in[2];
  const float* lnb  = (const float*)d_in[3];
  const float* Wq   = (const float*)d_in[4];
  const float* bq   = (const float*)d_in[5];
  const float* Wk   = (const float*)d_in[6];
  const float* bk   = (const float*)d_in[7];
  const float* Wv   = (const float*)d_in[8];
  const float* bv   = (const float*)d_in[9];
  const float* Wg   = (const float*)d_in[10];
  const float* bg   = (const float*)d_in[11];
  const float* Wo   = (const float*)d_in[12];
  const float* bo   = (const float*)d_in[13];
  float* out = (float*)d_out;

  const size_t elems = (size_t)MROWS * DCC;  // 8,388,608 halves per buffer
  __half* qb    = (__half*)d_ws;
  __half* kbuf  = qb    + elems;
  __half* vbuf  = kbuf  + elems;
  __half* gateb = vbuf  + elems;
  __half* zcom  = gateb + elems;   // total ws use: 5 * 16.78 MB = 83.9 MB

  k1_ln_qkvg<<<MROWS/128, 256, 0, stream>>>(z, lng, lnb, Wq, bq, Wk, bk,
                                            Wv, bv, Wg, bg, qb, kbuf, vbuf, gateb);
  k2_attn<<<LDIM*HN, 256, 0, stream>>>(qb, kbuf, vbuf, gateb, dist, zcom);
  k3_out<<<MROWS/128, 256, 0, stream>>>(zcom, Wo, bo, out);
}

// Round 2
// 291.285 us; speedup vs baseline: 1.5734x; 1.5734x over previous
//
#include <hip/hip_runtime.h>
#include <hip/hip_fp16.h>

#define LDIM 256
#define NDIM 256
#define DZC  128
#define HN   4
#define DHD  32
#define DCC  128
#define MROWS (LDIM*NDIM)

typedef unsigned int u32;
typedef _Float16 f16;
typedef _Float16 f16x8 __attribute__((ext_vector_type(8)));
typedef float    f32x4 __attribute__((ext_vector_type(4)));

__device__ inline u32 pack2(float a, float b){
  __half2 h = __floats2half2_rn(a, b);
  return *reinterpret_cast<u32*>(&h);
}
__device__ inline float2 up2(u32 u){
  __half2 h = *reinterpret_cast<__half2*>(&u);
  return __half22float2(h);
}

// ---------------- K1: LayerNorm + Q/K/V/Gate projections (unchanged) ----------------
__global__ __launch_bounds__(256) void k1_ln_qkvg(
    const float* __restrict__ z, const float* __restrict__ lng, const float* __restrict__ lnb,
    const float* __restrict__ Wq, const float* __restrict__ bq,
    const float* __restrict__ Wk, const float* __restrict__ bk,
    const float* __restrict__ Wv, const float* __restrict__ bv,
    const float* __restrict__ Wg, const float* __restrict__ bg,
    __half* __restrict__ qb, __half* __restrict__ kbuf,
    __half* __restrict__ vbuf, __half* __restrict__ gateb)
{
  __shared__ float zl[128*129];
  const int t = threadIdx.x;
  const int row0 = blockIdx.x * 128;

  { // LayerNorm: 2 threads per row, 64 elems each
    const int r = t >> 1, hf = t & 1;
    const float* zr = z + (size_t)(row0 + r) * DZC + hf*64;
    float vals[64];
    float s = 0.f, sq = 0.f;
    #pragma unroll
    for (int i = 0; i < 16; ++i) {
      float4 v4 = reinterpret_cast<const float4*>(zr)[i];
      vals[i*4+0]=v4.x; vals[i*4+1]=v4.y; vals[i*4+2]=v4.z; vals[i*4+3]=v4.w;
      s  += v4.x+v4.y+v4.z+v4.w;
      sq += v4.x*v4.x + v4.y*v4.y + v4.z*v4.z + v4.w*v4.w;
    }
    s  += __shfl_xor(s, 1);
    sq += __shfl_xor(sq, 1);
    const float mu  = s * (1.f/DZC);
    const float var = sq * (1.f/DZC) - mu*mu;
    const float rstd = rsqrtf(var + 1e-5f);
    const float* gg = lng + hf*64;
    const float* bb = lnb + hf*64;
    float* dst = &zl[r*129 + hf*64];
    #pragma unroll
    for (int i = 0; i < 64; ++i) dst[i] = (vals[i]-mu)*rstd*gg[i] + bb[i];
  }
  __syncthreads();

  const int cg = t & 15, rg = t >> 4;
  const float* Ws[4]  = {Wq, Wk, Wv, Wg};
  const float* bs[4]  = {bq, bk, bv, bg};
  __half* outs[3] = {qb, kbuf, vbuf};
  #pragma unroll
  for (int p = 0; p < 4; ++p) {
    float bias[8];
    #pragma unroll
    for (int cc=0;cc<8;++cc) bias[cc] = bs[p][cg*8+cc];
    float acc[8][8];
    #pragma unroll
    for (int rr=0;rr<8;++rr)
      #pragma unroll
      for (int cc=0;cc<8;++cc) acc[rr][cc] = bias[cc];

    const float* W = Ws[p];
    for (int c = 0; c < DZC; ++c) {
      const float4 w0 = *reinterpret_cast<const float4*>(W + c*DCC + cg*8);
      const float4 w1 = *reinterpret_cast<const float4*>(W + c*DCC + cg*8 + 4);
      const float wv[8] = {w0.x,w0.y,w0.z,w0.w,w1.x,w1.y,w1.z,w1.w};
      #pragma unroll
      for (int rr=0;rr<8;++rr){
        const float zv = zl[(rg*8+rr)*129 + c];
        #pragma unroll
        for (int cc=0;cc<8;++cc) acc[rr][cc] += zv * wv[cc];
      }
    }

    if (p < 3) {
      __half* ob = outs[p];
      const int hh = cg >> 2, dh0 = (cg & 3) * 8;
      #pragma unroll
      for (int rr=0;rr<8;++rr){
        const int row = row0 + rg*8 + rr;
        const int l = row >> 8, i = row & 255;
        uint4 u;
        u.x = pack2(acc[rr][0], acc[rr][1]);
        u.y = pack2(acc[rr][2], acc[rr][3]);
        u.z = pack2(acc[rr][4], acc[rr][5]);
        u.w = pack2(acc[rr][6], acc[rr][7]);
        *reinterpret_cast<uint4*>(ob + ((size_t)((l*HN + hh)*NDIM + i))*DHD + dh0) = u;
      }
    } else {
      #pragma unroll
      for (int rr=0;rr<8;++rr){
        const int row = row0 + rg*8 + rr;
        float gv[8];
        #pragma unroll
        for (int cc=0;cc<8;++cc) gv[cc] = 1.f/(1.f + __expf(-acc[rr][cc]));
        uint4 u;
        u.x = pack2(gv[0],gv[1]); u.y = pack2(gv[2],gv[3]);
        u.z = pack2(gv[4],gv[5]); u.w = pack2(gv[6],gv[7]);
        *reinterpret_cast<uint4*>(gateb + (size_t)row*DCC + cg*8) = u;
      }
    }
  }
}

// ---------------- K2: MFMA fused attention per (l, h) ----------------
// 4 waves x 64 query rows. QK^T and PV on matrix pipe (16x16x32 f16).
// P transits wave-private LDS (XOR-swizzled, conflict-free); V transposed
// once into shared LDS for B-fragments. coef computed inline from dist;
// 4 h-blocks of each l share dist[l] via XCD-swizzled block order.
#define PSTR 72    // P row stride in halves (16B-aligned b128 reads)
#define VSTR 264   // VT row stride in halves

__global__ __launch_bounds__(256, 2) void k2_attn(
    const f16* __restrict__ qb, const f16* __restrict__ kbuf,
    const f16* __restrict__ vbuf, const f16* __restrict__ gateb,
    const float* __restrict__ dist, f16* __restrict__ zcom)
{
  __shared__ f16 pl[4*64*PSTR];   // 36864 B, wave-private quarters
  __shared__ f16 vt[32*VSTR];     // 16896 B, shared V^T
  const int t = threadIdx.x;
  const int w = t >> 6, lane = t & 63;
  const int m = lane & 15, g = lane >> 4;
  const int orig = blockIdx.x;
  const int swz = (orig & 7)*128 + (orig >> 3);   // bijective XCD swizzle (1024 % 8 == 0)
  const int l = swz >> 2, h = swz & 3;
  const size_t hb = (size_t)(l*HN + h) * (NDIM*DHD);

  // ---- build VT[c][j] = V[j][c], j-swizzled by (c&3)<<3 ----
  {
    const f16x8* vg = reinterpret_cast<const f16x8*>(vbuf + hb + (size_t)t*DHD);
    #pragma unroll
    for (int p = 0; p < 4; ++p) {
      f16x8 v = vg[p];
      #pragma unroll
      for (int e = 0; e < 8; ++e) {
        const int c = p*8 + e;
        vt[c*VSTR + (t ^ ((c & 3) << 3))] = v[e];
      }
    }
  }

  // ---- Q A-fragments: lane holds Q[i = w*64+it*16+m][k = g*8..g*8+7] ----
  f16x8 aq[4];
  #pragma unroll
  for (int it = 0; it < 4; ++it)
    aq[it] = *reinterpret_cast<const f16x8*>(qb + hb + (size_t)(w*64 + it*16 + m)*DHD + g*8);

  f32x4 o[4][2];
  float rsum[4][4];
  #pragma unroll
  for (int it = 0; it < 4; ++it) {
    o[it][0] = (f32x4){0.f,0.f,0.f,0.f};
    o[it][1] = (f32x4){0.f,0.f,0.f,0.f};
    #pragma unroll
    for (int r = 0; r < 4; ++r) rsum[it][r] = 0.f;
  }

  __syncthreads();

  const float scalar = 0.17677669529663687f;  // 1/sqrt(32)
  const float* drow = dist + (size_t)l*NDIM*NDIM;
  f16* plw = pl + w*64*PSTR;

  for (int jc = 0; jc < 4; ++jc) {
    // K B-fragments: lane holds K[j = jc*64+jt*16+m][k = g*8..]
    f16x8 bk[4];
    #pragma unroll
    for (int jt = 0; jt < 4; ++jt)
      bk[jt] = *reinterpret_cast<const f16x8*>(kbuf + hb + (size_t)(jc*64 + jt*16 + m)*DHD + g*8);

    // QK^T: S[64 x 64] chunk, D-frag: row = g*4+r (+16*it), col = m (+16*jt)
    f32x4 s[4][4];
    #pragma unroll
    for (int it = 0; it < 4; ++it)
      #pragma unroll
      for (int jt = 0; jt < 4; ++jt)
        s[it][jt] = __builtin_amdgcn_mfma_f32_16x16x32_f16(
            aq[it], bk[jt], (f32x4){0.f,0.f,0.f,0.f}, 0, 0, 0);

    // coef * logit, exp (no-max softmax: logits tiny), rowsum, P -> LDS (f16)
    #pragma unroll
    for (int it = 0; it < 4; ++it) {
      #pragma unroll
      for (int r = 0; r < 4; ++r) {
        const int il = it*16 + g*4 + r;        // wave-local row
        const int ig = w*64 + il;              // head-local row
        #pragma unroll
        for (int jt = 0; jt < 4; ++jt) {
          const int jl = jt*16 + m;            // chunk-local col
          const float dv = drow[(size_t)ig*NDIM + jc*64 + jl];
          const float coef = __expf(dv*dv*(-1.f/128.f));
          const float p = __expf(s[it][jt][r]*coef*scalar);
          rsum[it][r] += p;
          plw[il*PSTR + (jl ^ ((il >> 2 & 3) << 4))] = (f16)p;  // il>>2&3 == g
        }
      }
    }
    __builtin_amdgcn_sched_barrier(0);

    // PV: O[64 x 32] += P[64 x 64] * V[64 x 32]
    #pragma unroll
    for (int kc = 0; kc < 2; ++kc) {
      f16x8 bv[2];
      #pragma unroll
      for (int ct = 0; ct < 2; ++ct)
        bv[ct] = *reinterpret_cast<const f16x8*>(
            vt + (ct*16 + m)*VSTR + ((jc*64 + kc*32 + g*8) ^ ((m & 3) << 3)));
      #pragma unroll
      for (int it = 0; it < 4; ++it) {
        f16x8 ap = *reinterpret_cast<const f16x8*>(
            plw + (it*16 + m)*PSTR + ((kc*32 + g*8) ^ (((m >> 2) & 3) << 4)));
        o[it][0] = __builtin_amdgcn_mfma_f32_16x16x32_f16(ap, bv[0], o[it][0], 0, 0, 0);
        o[it][1] = __builtin_amdgcn_mfma_f32_16x16x32_f16(ap, bv[1], o[it][1], 0, 0, 0);
      }
    }
  }

  // ---- row-sum reduce across the 16 lanes of each group, invert ----
  #pragma unroll
  for (int it = 0; it < 4; ++it)
    #pragma unroll
    for (int r = 0; r < 4; ++r) {
      float v = rsum[it][r];
      v += __shfl_xor(v, 1); v += __shfl_xor(v, 2);
      v += __shfl_xor(v, 4); v += __shfl_xor(v, 8);
      rsum[it][r] = 1.f / v;
    }

  // ---- epilogue: normalize, gate, store z_com ----
  #pragma unroll
  for (int it = 0; it < 4; ++it)
    #pragma unroll
    for (int ct = 0; ct < 2; ++ct)
      #pragma unroll
      for (int r = 0; r < 4; ++r) {
        const int row = l*NDIM + w*64 + it*16 + g*4 + r;
        const int col = h*DHD + ct*16 + m;
        const float gv = (float)gateb[(size_t)row*DCC + col];
        zcom[(size_t)row*DCC + col] = (f16)(o[it][ct][r] * rsum[it][r] * gv);
      }
}

// ---------------- K3: output projection (unchanged) ----------------
__global__ __launch_bounds__(256) void k3_out(
    const __half* __restrict__ zcom, const float* __restrict__ Wo,
    const float* __restrict__ bo, float* __restrict__ out)
{
  __shared__ float zl[128*129];
  const int t = threadIdx.x;
  const int row0 = blockIdx.x * 128;
  {
    const int r = t >> 1, hf = t & 1;
    const uint4* zr = reinterpret_cast<const uint4*>(zcom + (size_t)(row0 + r)*DCC + hf*64);
    float* dst = &zl[r*129 + hf*64];
    #pragma unroll
    for (int i = 0; i < 8; ++i) {
      uint4 u = zr[i];
      float2 f0 = up2(u.x), f1 = up2(u.y), f2 = up2(u.z), f3 = up2(u.w);
      dst[i*8+0]=f0.x; dst[i*8+1]=f0.y; dst[i*8+2]=f1.x; dst[i*8+3]=f1.y;
      dst[i*8+4]=f2.x; dst[i*8+5]=f2.y; dst[i*8+6]=f3.x; dst[i*8+7]=f3.y;
    }
  }
  __syncthreads();
  const int cg = t & 15, rg = t >> 4;
  float bias[8];
  #pragma unroll
  for (int cc=0;cc<8;++cc) bias[cc] = bo[cg*8+cc];
  float acc[8][8];
  #pragma unroll
  for (int rr=0;rr<8;++rr)
    #pragma unroll
    for (int cc=0;cc<8;++cc) acc[rr][cc] = bias[cc];
  for (int c = 0; c < DCC; ++c) {
    const float4 w0 = *reinterpret_cast<const float4*>(Wo + c*DZC + cg*8);
    const float4 w1 = *reinterpret_cast<const float4*>(Wo + c*DZC + cg*8 + 4);
    const float wv[8] = {w0.x,w0.y,w0.z,w0.w,w1.x,w1.y,w1.z,w1.w};
    #pragma unroll
    for (int rr=0;rr<8;++rr){
      const float zv = zl[(rg*8+rr)*129 + c];
      #pragma unroll
      for (int cc=0;cc<8;++cc) acc[rr][cc] += zv*wv[cc];
    }
  }
  #pragma unroll
  for (int rr=0;rr<8;++rr){
    float* orow = out + (size_t)(row0 + rg*8 + rr)*DZC + cg*8;
    reinterpret_cast<float4*>(orow)[0] = make_float4(acc[rr][0],acc[rr][1],acc[rr][2],acc[rr][3]);
    reinterpret_cast<float4*>(orow)[1] = make_float4(acc[rr][4],acc[rr][5],acc[rr][6],acc[rr][7]);
  }
}

extern "C" void kernel_launch(void* const* d_in, const int* in_sizes, int n_in,
                              void* d_out, int out_size, void* d_ws, size_t ws_size,
                              hipStream_t stream) {
  const float* z    = (const float*)d_in[0];
  const float* dist = (const float*)d_in[1];
  const float* lng  = (const float*)d_in[2];
  const float* lnb  = (const float*)d_in[3];
  const float* Wq   = (const float*)d_in[4];
  const float* bq   = (const float*)d_in[5];
  const float* Wk   = (const float*)d_in[6];
  const float* bk   = (const float*)d_in[7];
  const float* Wv   = (const float*)d_in[8];
  const float* bv   = (const float*)d_in[9];
  const float* Wg   = (const float*)d_in[10];
  const float* bg   = (const float*)d_in[11];
  const float* Wo   = (const float*)d_in[12];
  const float* bo   = (const float*)d_in[13];
  float* out = (float*)d_out;

  const size_t elems = (size_t)MROWS * DCC;
  __half* qb    = (__half*)d_ws;
  __half* kbuf  = qb    + elems;
  __half* vbuf  = kbuf  + elems;
  __half* gateb = vbuf  + elems;
  __half* zcom  = gateb + elems;

  k1_ln_qkvg<<<MROWS/128, 256, 0, stream>>>(z, lng, lnb, Wq, bq, Wk, bk,
                                            Wv, bv, Wg, bg, qb, kbuf, vbuf, gateb);
  k2_attn<<<LDIM*HN, 256, 0, stream>>>((const f16*)qb, (const f16*)kbuf,
                                       (const f16*)vbuf, (const f16*)gateb,
                                       dist, (f16*)zcom);
  k3_out<<<MROWS/128, 256, 0, stream>>>(zcom, Wo, bo, out);
}

// Round 3
// 220.092 us; speedup vs baseline: 2.0823x; 1.3235x over previous
//
#include <hip/hip_runtime.h>
#include <hip/hip_fp16.h>

#define LDIM 256
#define NDIM 256
#define DZC  128
#define HN   4
#define DHD  32
#define DCC  128
#define MROWS (LDIM*NDIM)

typedef unsigned int u32;
typedef _Float16 f16;
typedef _Float16 f16x4 __attribute__((ext_vector_type(4)));
typedef _Float16 f16x8 __attribute__((ext_vector_type(8)));
typedef float    f32x4 __attribute__((ext_vector_type(4)));

__device__ inline u32 pack2(float a, float b){
  __half2 h = __floats2half2_rn(a, b);
  return *reinterpret_cast<u32*>(&h);
}
__device__ inline float2 up2(u32 u){
  __half2 h = *reinterpret_cast<__half2*>(&u);
  return __half22float2(h);
}

// ---------------- K0: coefp = (1/sqrt(DH)) * exp(-(d/8)^2/2), f16 ----------------
__global__ __launch_bounds__(256) void k0_coef(
    const float* __restrict__ dist, f16* __restrict__ coefp)
{
  const size_t base = ((size_t)blockIdx.x * 256 + threadIdx.x) * 8;
  const float4 a = *reinterpret_cast<const float4*>(dist + base);
  const float4 b = *reinterpret_cast<const float4*>(dist + base + 4);
  const float dv[8] = {a.x,a.y,a.z,a.w,b.x,b.y,b.z,b.w};
  f16x8 o;
  #pragma unroll
  for (int r = 0; r < 8; ++r)
    o[r] = (f16)(0.17677669529663687f * __expf(dv[r]*dv[r]*(-1.f/128.f)));
  *reinterpret_cast<f16x8*>(coefp + base) = o;
}

// ---------------- K1: LayerNorm + Q/K/V/Gate projections (unchanged) ----------------
__global__ __launch_bounds__(256) void k1_ln_qkvg(
    const float* __restrict__ z, const float* __restrict__ lng, const float* __restrict__ lnb,
    const float* __restrict__ Wq, const float* __restrict__ bq,
    const float* __restrict__ Wk, const float* __restrict__ bk,
    const float* __restrict__ Wv, const float* __restrict__ bv,
    const float* __restrict__ Wg, const float* __restrict__ bg,
    __half* __restrict__ qb, __half* __restrict__ kbuf,
    __half* __restrict__ vbuf, __half* __restrict__ gateb)
{
  __shared__ float zl[128*129];
  const int t = threadIdx.x;
  const int row0 = blockIdx.x * 128;

  { // LayerNorm: 2 threads per row, 64 elems each
    const int r = t >> 1, hf = t & 1;
    const float* zr = z + (size_t)(row0 + r) * DZC + hf*64;
    float vals[64];
    float s = 0.f, sq = 0.f;
    #pragma unroll
    for (int i = 0; i < 16; ++i) {
      float4 v4 = reinterpret_cast<const float4*>(zr)[i];
      vals[i*4+0]=v4.x; vals[i*4+1]=v4.y; vals[i*4+2]=v4.z; vals[i*4+3]=v4.w;
      s  += v4.x+v4.y+v4.z+v4.w;
      sq += v4.x*v4.x + v4.y*v4.y + v4.z*v4.z + v4.w*v4.w;
    }
    s  += __shfl_xor(s, 1);
    sq += __shfl_xor(sq, 1);
    const float mu  = s * (1.f/DZC);
    const float var = sq * (1.f/DZC) - mu*mu;
    const float rstd = rsqrtf(var + 1e-5f);
    const float* gg = lng + hf*64;
    const float* bb = lnb + hf*64;
    float* dst = &zl[r*129 + hf*64];
    #pragma unroll
    for (int i = 0; i < 64; ++i) dst[i] = (vals[i]-mu)*rstd*gg[i] + bb[i];
  }
  __syncthreads();

  const int cg = t & 15, rg = t >> 4;
  const float* Ws[4]  = {Wq, Wk, Wv, Wg};
  const float* bs[4]  = {bq, bk, bv, bg};
  __half* outs[3] = {qb, kbuf, vbuf};
  #pragma unroll
  for (int p = 0; p < 4; ++p) {
    float bias[8];
    #pragma unroll
    for (int cc=0;cc<8;++cc) bias[cc] = bs[p][cg*8+cc];
    float acc[8][8];
    #pragma unroll
    for (int rr=0;rr<8;++rr)
      #pragma unroll
      for (int cc=0;cc<8;++cc) acc[rr][cc] = bias[cc];

    const float* W = Ws[p];
    for (int c = 0; c < DZC; ++c) {
      const float4 w0 = *reinterpret_cast<const float4*>(W + c*DCC + cg*8);
      const float4 w1 = *reinterpret_cast<const float4*>(W + c*DCC + cg*8 + 4);
      const float wv[8] = {w0.x,w0.y,w0.z,w0.w,w1.x,w1.y,w1.z,w1.w};
      #pragma unroll
      for (int rr=0;rr<8;++rr){
        const float zv = zl[(rg*8+rr)*129 + c];
        #pragma unroll
        for (int cc=0;cc<8;++cc) acc[rr][cc] += zv * wv[cc];
      }
    }

    if (p < 3) {
      __half* ob = outs[p];
      const int hh = cg >> 2, dh0 = (cg & 3) * 8;
      #pragma unroll
      for (int rr=0;rr<8;++rr){
        const int row = row0 + rg*8 + rr;
        const int l = row >> 8, i = row & 255;
        uint4 u;
        u.x = pack2(acc[rr][0], acc[rr][1]);
        u.y = pack2(acc[rr][2], acc[rr][3]);
        u.z = pack2(acc[rr][4], acc[rr][5]);
        u.w = pack2(acc[rr][6], acc[rr][7]);
        *reinterpret_cast<uint4*>(ob + ((size_t)((l*HN + hh)*NDIM + i))*DHD + dh0) = u;
      }
    } else {
      #pragma unroll
      for (int rr=0;rr<8;++rr){
        const int row = row0 + rg*8 + rr;
        float gv[8];
        #pragma unroll
        for (int cc=0;cc<8;++cc) gv[cc] = 1.f/(1.f + __expf(-acc[rr][cc]));
        uint4 u;
        u.x = pack2(gv[0],gv[1]); u.y = pack2(gv[2],gv[3]);
        u.z = pack2(gv[4],gv[5]); u.w = pack2(gv[6],gv[7]);
        *reinterpret_cast<uint4*>(gateb + (size_t)row*DCC + cg*8) = u;
      }
    }
  }
}

// ---------------- K2: MFMA fused attention per (l, h), swapped-QK layout ----------------
// S^T = K*Q^T via mfma(K-frag, Q-frag): lane holds P[i=m][4 consecutive j] per reg.
// coef: one f16x4 load / 4 elems; P: one ds_write_b64 / 4 elems; P row-major
// feeds PV A-frags as aligned b128 reads. rowsum lane-local + 2 shfl_xor.
#define PSTR 72    // P row stride in halves (144B: write 2-way free, b128 reads at floor)
#define VSTR 264   // VT row stride in halves

__global__ __launch_bounds__(256, 2) void k2_attn(
    const f16* __restrict__ qb, const f16* __restrict__ kbuf,
    const f16* __restrict__ vbuf, const f16* __restrict__ gateb,
    const f16* __restrict__ coefp, f16* __restrict__ zcom)
{
  __shared__ f16 pl[4*64*PSTR];   // 36864 B, wave-private quarters
  __shared__ f16 vt[32*VSTR];     // 16896 B, shared V^T
  const int t = threadIdx.x;
  const int w = t >> 6, lane = t & 63;
  const int m = lane & 15, g = lane >> 4;
  const int orig = blockIdx.x;
  const int swz = (orig & 7)*128 + (orig >> 3);   // bijective XCD swizzle (1024 % 8 == 0)
  const int l = swz >> 2, h = swz & 3;
  const size_t hb = (size_t)(l*HN + h) * (NDIM*DHD);

  // ---- build VT[c][j] = V[j][c], j-swizzled by (c&3)<<3 ----
  {
    const f16x8* vg = reinterpret_cast<const f16x8*>(vbuf + hb + (size_t)t*DHD);
    #pragma unroll
    for (int p = 0; p < 4; ++p) {
      f16x8 v = vg[p];
      #pragma unroll
      for (int e = 0; e < 8; ++e) {
        const int c = p*8 + e;
        vt[c*VSTR + (t ^ ((c & 3) << 3))] = v[e];
      }
    }
  }

  // ---- Q fragments: lane holds Q[i = w*64+it*16+m][k = g*8..g*8+7] (B-operand) ----
  f16x8 aq[4];
  #pragma unroll
  for (int it = 0; it < 4; ++it)
    aq[it] = *reinterpret_cast<const f16x8*>(qb + hb + (size_t)(w*64 + it*16 + m)*DHD + g*8);

  f32x4 o[4][2];
  float rs[4];
  #pragma unroll
  for (int it = 0; it < 4; ++it) {
    o[it][0] = (f32x4){0.f,0.f,0.f,0.f};
    o[it][1] = (f32x4){0.f,0.f,0.f,0.f};
    rs[it] = 0.f;
  }

  __syncthreads();

  const f16* crow = coefp + (size_t)l*(NDIM*NDIM);
  f16* plw = pl + w*64*PSTR;

  for (int jc = 0; jc < 4; ++jc) {
    // K fragments (A-operand): lane holds K[j = jc*64+jt*16+m][k = g*8..]
    f16x8 bk[4];
    #pragma unroll
    for (int jt = 0; jt < 4; ++jt)
      bk[jt] = *reinterpret_cast<const f16x8*>(kbuf + hb + (size_t)(jc*64 + jt*16 + m)*DHD + g*8);

    #pragma unroll
    for (int it = 0; it < 4; ++it) {
      // S^T tiles: D row = j-local (g*4+r), col = i-local (m)
      f32x4 s[4];
      #pragma unroll
      for (int jt = 0; jt < 4; ++jt)
        s[jt] = __builtin_amdgcn_mfma_f32_16x16x32_f16(
            bk[jt], aq[it], (f32x4){0.f,0.f,0.f,0.f}, 0, 0, 0);

      const int i = w*64 + it*16 + m;       // this lane's query row
      #pragma unroll
      for (int jt = 0; jt < 4; ++jt) {
        const int j0 = jc*64 + jt*16 + g*4; // 4 consecutive j
        const f16x4 cp = *reinterpret_cast<const f16x4*>(crow + (size_t)i*NDIM + j0);
        f16x4 pk;
        float psum = 0.f;
        #pragma unroll
        for (int r = 0; r < 4; ++r) {
          const float p = __expf(s[jt][r] * (float)cp[r]);  // no-max softmax: logits tiny
          psum += p;
          pk[r] = (f16)p;
        }
        rs[it] += psum;
        *reinterpret_cast<f16x4*>(plw + (it*16 + m)*PSTR + jt*16 + g*4) = pk;
      }
    }
    __builtin_amdgcn_sched_barrier(0);

    // PV: O[64 x 32] += P[64 x 64] * V[64 x 32]
    #pragma unroll
    for (int kc = 0; kc < 2; ++kc) {
      f16x8 bv[2];
      #pragma unroll
      for (int ct = 0; ct < 2; ++ct)
        bv[ct] = *reinterpret_cast<const f16x8*>(
            vt + (ct*16 + m)*VSTR + ((jc*64 + kc*32 + g*8) ^ ((m & 3) << 3)));
      #pragma unroll
      for (int it = 0; it < 4; ++it) {
        f16x8 ap = *reinterpret_cast<const f16x8*>(
            plw + (it*16 + m)*PSTR + kc*32 + g*8);
        o[it][0] = __builtin_amdgcn_mfma_f32_16x16x32_f16(ap, bv[0], o[it][0], 0, 0, 0);
        o[it][1] = __builtin_amdgcn_mfma_f32_16x16x32_f16(ap, bv[1], o[it][1], 0, 0, 0);
      }
    }
    __builtin_amdgcn_sched_barrier(0);
  }

  // ---- rowsum: lane-local + reduce across g-quarters (same m) ----
  float rinv[4];
  #pragma unroll
  for (int it = 0; it < 4; ++it) {
    float v = rs[it];
    v += __shfl_xor(v, 16);
    v += __shfl_xor(v, 32);
    rinv[it] = 1.f / v;
  }

  // ---- epilogue: normalize (rinv lives at lane m=row%16), gate, store ----
  #pragma unroll
  for (int it = 0; it < 4; ++it)
    #pragma unroll
    for (int r = 0; r < 4; ++r) {
      const float rr = __shfl(rinv[it], (lane & 48) + g*4 + r);
      const int row = l*NDIM + w*64 + it*16 + g*4 + r;
      #pragma unroll
      for (int ct = 0; ct < 2; ++ct) {
        const int col = h*DHD + ct*16 + m;
        const float gv = (float)gateb[(size_t)row*DCC + col];
        zcom[(size_t)row*DCC + col] = (f16)(o[it][ct][r] * rr * gv);
      }
    }
}

// ---------------- K3: output projection (unchanged) ----------------
__global__ __launch_bounds__(256) void k3_out(
    const __half* __restrict__ zcom, const float* __restrict__ Wo,
    const float* __restrict__ bo, float* __restrict__ out)
{
  __shared__ float zl[128*129];
  const int t = threadIdx.x;
  const int row0 = blockIdx.x * 128;
  {
    const int r = t >> 1, hf = t & 1;
    const uint4* zr = reinterpret_cast<const uint4*>(zcom + (size_t)(row0 + r)*DCC + hf*64);
    float* dst = &zl[r*129 + hf*64];
    #pragma unroll
    for (int i = 0; i < 8; ++i) {
      uint4 u = zr[i];
      float2 f0 = up2(u.x), f1 = up2(u.y), f2 = up2(u.z), f3 = up2(u.w);
      dst[i*8+0]=f0.x; dst[i*8+1]=f0.y; dst[i*8+2]=f1.x; dst[i*8+3]=f1.y;
      dst[i*8+4]=f2.x; dst[i*8+5]=f2.y; dst[i*8+6]=f3.x; dst[i*8+7]=f3.y;
    }
  }
  __syncthreads();
  const int cg = t & 15, rg = t >> 4;
  float bias[8];
  #pragma unroll
  for (int cc=0;cc<8;++cc) bias[cc] = bo[cg*8+cc];
  float acc[8][8];
  #pragma unroll
  for (int rr=0;rr<8;++rr)
    #pragma unroll
    for (int cc=0;cc<8;++cc) acc[rr][cc] = bias[cc];
  for (int c = 0; c < DCC; ++c) {
    const float4 w0 = *reinterpret_cast<const float4*>(Wo + c*DZC + cg*8);
    const float4 w1 = *reinterpret_cast<const float4*>(Wo + c*DZC + cg*8 + 4);
    const float wv[8] = {w0.x,w0.y,w0.z,w0.w,w1.x,w1.y,w1.z,w1.w};
    #pragma unroll
    for (int rr=0;rr<8;++rr){
      const float zv = zl[(rg*8+rr)*129 + c];
      #pragma unroll
      for (int cc=0;cc<8;++cc) acc[rr][cc] += zv*wv[cc];
    }
  }
  #pragma unroll
  for (int rr=0;rr<8;++rr){
    float* orow = out + (size_t)(row0 + rg*8 + rr)*DZC + cg*8;
    reinterpret_cast<float4*>(orow)[0] = make_float4(acc[rr][0],acc[rr][1],acc[rr][2],acc[rr][3]);
    reinterpret_cast<float4*>(orow)[1] = make_float4(acc[rr][4],acc[rr][5],acc[rr][6],acc[rr][7]);
  }
}

extern "C" void kernel_launch(void* const* d_in, const int* in_sizes, int n_in,
                              void* d_out, int out_size, void* d_ws, size_t ws_size,
                              hipStream_t stream) {
  const float* z    = (const float*)d_in[0];
  const float* dist = (const float*)d_in[1];
  const float* lng  = (const float*)d_in[2];
  const float* lnb  = (const float*)d_in[3];
  const float* Wq   = (const float*)d_in[4];
  const float* bq   = (const float*)d_in[5];
  const float* Wk   = (const float*)d_in[6];
  const float* bk   = (const float*)d_in[7];
  const float* Wv   = (const float*)d_in[8];
  const float* bv   = (const float*)d_in[9];
  const float* Wg   = (const float*)d_in[10];
  const float* bg   = (const float*)d_in[11];
  const float* Wo   = (const float*)d_in[12];
  const float* bo   = (const float*)d_in[13];
  float* out = (float*)d_out;

  const size_t elems = (size_t)MROWS * DCC;  // 8,388,608
  __half* qb    = (__half*)d_ws;
  __half* kbuf  = qb    + elems;
  __half* vbuf  = kbuf  + elems;
  __half* gateb = vbuf  + elems;
  __half* zcom  = gateb + elems;
  f16*    coefp = (f16*)(zcom + elems);   // 16,777,216 halves; total ws ≈ 117 MB

  k0_coef<<<(LDIM*NDIM*NDIM)/(256*8), 256, 0, stream>>>(dist, coefp);
  k1_ln_qkvg<<<MROWS/128, 256, 0, stream>>>(z, lng, lnb, Wq, bq, Wk, bk,
                                            Wv, bv, Wg, bg, qb, kbuf, vbuf, gateb);
  k2_attn<<<LDIM*HN, 256, 0, stream>>>((const f16*)qb, (const f16*)kbuf,
                                       (const f16*)vbuf, (const f16*)gateb,
                                       coefp, (f16*)zcom);
  k3_out<<<MROWS/128, 256, 0, stream>>>(zcom, Wo, bo, out);
}

// Round 4
// 128.181 us; speedup vs baseline: 3.5755x; 1.7170x over previous
//
#include <hip/hip_runtime.h>
#include <hip/hip_fp16.h>

#define LDIM 256
#define NDIM 256
#define DZC  128
#define HN   4
#define DHD  32
#define DCC  128
#define MROWS (LDIM*NDIM)

typedef unsigned int u32;
typedef _Float16 f16;
typedef _Float16 f16x4 __attribute__((ext_vector_type(4)));
typedef _Float16 f16x8 __attribute__((ext_vector_type(8)));
typedef float    f32x4 __attribute__((ext_vector_type(4)));

// ---------------- K0a: coefp = (1/sqrt(DH)) * exp(-(d/8)^2/2), f16 ----------------
__global__ __launch_bounds__(256) void k0_coef(
    const float* __restrict__ dist, f16* __restrict__ coefp)
{
  const size_t base = ((size_t)blockIdx.x * 256 + threadIdx.x) * 8;
  const float4 a = *reinterpret_cast<const float4*>(dist + base);
  const float4 b = *reinterpret_cast<const float4*>(dist + base + 4);
  const float dv[8] = {a.x,a.y,a.z,a.w,b.x,b.y,b.z,b.w};
  f16x8 o;
  #pragma unroll
  for (int r = 0; r < 8; ++r)
    o[r] = (f16)(0.17677669529663687f * __expf(dv[r]*dv[r]*(-1.f/128.f)));
  *reinterpret_cast<f16x8*>(coefp + base) = o;
}

// ---------------- K0b: pack W^T f16 — w16[p][col][k] = W_p[k][col] ----------------
// p: 0=Wq 1=Wk 2=Wv 3=Wg 4=Wo. 5*16384 elems, grid 320x256.
__global__ __launch_bounds__(256) void k0b_pack(
    const float* __restrict__ Wq, const float* __restrict__ Wk,
    const float* __restrict__ Wv, const float* __restrict__ Wg,
    const float* __restrict__ Wo, f16* __restrict__ w16)
{
  const float* Ws[5] = {Wq, Wk, Wv, Wg, Wo};
  const int tid = blockIdx.x * 256 + threadIdx.x;
  const int p = tid >> 14, rem = tid & 16383;
  const int col = rem >> 7, k = rem & 127;
  w16[tid] = (f16)Ws[p][k*128 + col];
}

// ---------------- K1: LN + Q/K/V/Gate via MFMA ----------------
// 64 rows/block, 4 waves: wave w = projection w. A = W^T frags (global, L2-hot),
// B = z_ln f16 frags (LDS, stride 136 -> even granule spread, conflict-free).
// D-layout (verified in k2): lane m = output row, regs = 4 consecutive cols.
__global__ __launch_bounds__(256, 2) void k1_ln_qkvg(
    const float* __restrict__ z, const float* __restrict__ lng, const float* __restrict__ lnb,
    const f16* __restrict__ w16,
    const float* __restrict__ bq, const float* __restrict__ bk,
    const float* __restrict__ bv, const float* __restrict__ bg,
    f16* __restrict__ qb, f16* __restrict__ kbuf,
    f16* __restrict__ vbuf, f16* __restrict__ gateb)
{
  __shared__ f16 zl[64*136];
  const int t = threadIdx.x;
  const int w = t >> 6, lane = t & 63;
  const int m = lane & 15, g = lane >> 4;
  const int row0 = blockIdx.x * 64;

  { // LayerNorm: 4 threads/row, 32 elems each -> f16 LDS
    const int r = t >> 2, part = t & 3;
    const float* zr = z + (size_t)(row0 + r)*DZC + part*32;
    float vals[32];
    float s = 0.f, sq = 0.f;
    #pragma unroll
    for (int i = 0; i < 8; ++i) {
      float4 v4 = reinterpret_cast<const float4*>(zr)[i];
      vals[i*4+0]=v4.x; vals[i*4+1]=v4.y; vals[i*4+2]=v4.z; vals[i*4+3]=v4.w;
      s  += v4.x+v4.y+v4.z+v4.w;
      sq += v4.x*v4.x + v4.y*v4.y + v4.z*v4.z + v4.w*v4.w;
    }
    s  += __shfl_xor(s, 1);  sq += __shfl_xor(sq, 1);
    s  += __shfl_xor(s, 2);  sq += __shfl_xor(sq, 2);
    const float mu  = s * (1.f/DZC);
    const float var = sq * (1.f/DZC) - mu*mu;
    const float rstd = rsqrtf(var + 1e-5f);
    const float* gg = lng + part*32;
    const float* bb = lnb + part*32;
    f16* dst = zl + r*136 + part*32;
    #pragma unroll
    for (int i = 0; i < 4; ++i) {
      f16x8 o;
      #pragma unroll
      for (int e = 0; e < 8; ++e)
        o[e] = (f16)((vals[i*8+e]-mu)*rstd*gg[i*8+e] + bb[i*8+e]);
      *reinterpret_cast<f16x8*>(dst + i*8) = o;
    }
  }
  __syncthreads();

  const f16* wp = w16 + w*16384;
  f32x4 acc[4][8];
  #pragma unroll
  for (int it=0;it<4;++it)
    #pragma unroll
    for (int jt=0;jt<8;++jt) acc[it][jt] = (f32x4){0.f,0.f,0.f,0.f};

  #pragma unroll
  for (int ks = 0; ks < 4; ++ks) {
    f16x8 af[8];
    #pragma unroll
    for (int jt=0;jt<8;++jt)
      af[jt] = *reinterpret_cast<const f16x8*>(wp + (jt*16+m)*128 + ks*32 + g*8);
    f16x8 bf[4];
    #pragma unroll
    for (int it=0;it<4;++it)
      bf[it] = *reinterpret_cast<const f16x8*>(zl + (it*16+m)*136 + ks*32 + g*8);
    #pragma unroll
    for (int it=0;it<4;++it)
      #pragma unroll
      for (int jt=0;jt<8;++jt)
        acc[it][jt] = __builtin_amdgcn_mfma_f32_16x16x32_f16(af[jt], bf[it], acc[it][jt], 0,0,0);
  }

  const float* bsp = (w==0) ? bq : (w==1) ? bk : (w==2) ? bv : bg;
  float4 bias[8];
  #pragma unroll
  for (int jt=0;jt<8;++jt)
    bias[jt] = *reinterpret_cast<const float4*>(bsp + jt*16 + g*4);

  const int l = row0 >> 8, i0 = row0 & 255;
  if (w < 3) {
    f16* ob = (w==0) ? qb : (w==1) ? kbuf : vbuf;
    #pragma unroll
    for (int it=0;it<4;++it) {
      const int i = i0 + it*16 + m;
      #pragma unroll
      for (int jt=0;jt<8;++jt) {
        const int hh = jt >> 1, dh0 = (jt&1)*16 + g*4;
        f16x4 o;
        #pragma unroll
        for (int r=0;r<4;++r) o[r] = (f16)(acc[it][jt][r] + ((const float*)&bias[jt])[r]);
        *reinterpret_cast<f16x4*>(ob + ((size_t)(l*HN + hh)*NDIM + i)*DHD + dh0) = o;
      }
    }
  } else {
    #pragma unroll
    for (int it=0;it<4;++it) {
      const int rowg = row0 + it*16 + m;
      #pragma unroll
      for (int jt=0;jt<8;++jt) {
        f16x4 o;
        #pragma unroll
        for (int r=0;r<4;++r) {
          const float v = acc[it][jt][r] + ((const float*)&bias[jt])[r];
          o[r] = (f16)(1.f/(1.f + __expf(-v)));
        }
        *reinterpret_cast<f16x4*>(gateb + (size_t)rowg*DCC + jt*16 + g*4) = o;
      }
    }
  }
}

// ---------------- K2: MFMA fused attention per (l, h), swapped-QK layout ----------------
#define PSTR 72    // P row stride in halves
#define VSTR 264   // VT row stride in halves

__global__ __launch_bounds__(256, 2) void k2_attn(
    const f16* __restrict__ qb, const f16* __restrict__ kbuf,
    const f16* __restrict__ vbuf, const f16* __restrict__ gateb,
    const f16* __restrict__ coefp, f16* __restrict__ zcom)
{
  __shared__ f16 pl[4*64*PSTR];   // 36864 B, wave-private quarters
  __shared__ f16 vt[32*VSTR];     // 16896 B, shared V^T
  const int t = threadIdx.x;
  const int w = t >> 6, lane = t & 63;
  const int m = lane & 15, g = lane >> 4;
  const int orig = blockIdx.x;
  const int swz = (orig & 7)*128 + (orig >> 3);   // bijective XCD swizzle
  const int l = swz >> 2, h = swz & 3;
  const size_t hb = (size_t)(l*HN + h) * (NDIM*DHD);

  { // build VT[c][j] = V[j][c], j-swizzled by (c&3)<<3
    const f16x8* vg = reinterpret_cast<const f16x8*>(vbuf + hb + (size_t)t*DHD);
    #pragma unroll
    for (int p = 0; p < 4; ++p) {
      f16x8 v = vg[p];
      #pragma unroll
      for (int e = 0; e < 8; ++e) {
        const int c = p*8 + e;
        vt[c*VSTR + (t ^ ((c & 3) << 3))] = v[e];
      }
    }
  }

  f16x8 aq[4];
  #pragma unroll
  for (int it = 0; it < 4; ++it)
    aq[it] = *reinterpret_cast<const f16x8*>(qb + hb + (size_t)(w*64 + it*16 + m)*DHD + g*8);

  f32x4 o[4][2];
  float rs[4];
  #pragma unroll
  for (int it = 0; it < 4; ++it) {
    o[it][0] = (f32x4){0.f,0.f,0.f,0.f};
    o[it][1] = (f32x4){0.f,0.f,0.f,0.f};
    rs[it] = 0.f;
  }

  __syncthreads();

  const f16* crow = coefp + (size_t)l*(NDIM*NDIM);
  f16* plw = pl + w*64*PSTR;

  for (int jc = 0; jc < 4; ++jc) {
    f16x8 bk[4];
    #pragma unroll
    for (int jt = 0; jt < 4; ++jt)
      bk[jt] = *reinterpret_cast<const f16x8*>(kbuf + hb + (size_t)(jc*64 + jt*16 + m)*DHD + g*8);

    #pragma unroll
    for (int it = 0; it < 4; ++it) {
      f32x4 s[4];
      #pragma unroll
      for (int jt = 0; jt < 4; ++jt)
        s[jt] = __builtin_amdgcn_mfma_f32_16x16x32_f16(
            bk[jt], aq[it], (f32x4){0.f,0.f,0.f,0.f}, 0, 0, 0);

      const int i = w*64 + it*16 + m;
      #pragma unroll
      for (int jt = 0; jt < 4; ++jt) {
        const int j0 = jc*64 + jt*16 + g*4;
        const f16x4 cp = *reinterpret_cast<const f16x4*>(crow + (size_t)i*NDIM + j0);
        f16x4 pk;
        float psum = 0.f;
        #pragma unroll
        for (int r = 0; r < 4; ++r) {
          const float p = __expf(s[jt][r] * (float)cp[r]);  // no-max softmax: logits tiny
          psum += p;
          pk[r] = (f16)p;
        }
        rs[it] += psum;
        *reinterpret_cast<f16x4*>(plw + (it*16 + m)*PSTR + jt*16 + g*4) = pk;
      }
    }
    __builtin_amdgcn_sched_barrier(0);

    #pragma unroll
    for (int kc = 0; kc < 2; ++kc) {
      f16x8 bv[2];
      #pragma unroll
      for (int ct = 0; ct < 2; ++ct)
        bv[ct] = *reinterpret_cast<const f16x8*>(
            vt + (ct*16 + m)*VSTR + ((jc*64 + kc*32 + g*8) ^ ((m & 3) << 3)));
      #pragma unroll
      for (int it = 0; it < 4; ++it) {
        f16x8 ap = *reinterpret_cast<const f16x8*>(
            plw + (it*16 + m)*PSTR + kc*32 + g*8);
        o[it][0] = __builtin_amdgcn_mfma_f32_16x16x32_f16(ap, bv[0], o[it][0], 0, 0, 0);
        o[it][1] = __builtin_amdgcn_mfma_f32_16x16x32_f16(ap, bv[1], o[it][1], 0, 0, 0);
      }
    }
    __builtin_amdgcn_sched_barrier(0);
  }

  float rinv[4];
  #pragma unroll
  for (int it = 0; it < 4; ++it) {
    float v = rs[it];
    v += __shfl_xor(v, 16);
    v += __shfl_xor(v, 32);
    rinv[it] = 1.f / v;
  }

  #pragma unroll
  for (int it = 0; it < 4; ++it)
    #pragma unroll
    for (int r = 0; r < 4; ++r) {
      const float rr = __shfl(rinv[it], (lane & 48) + g*4 + r);
      const int row = l*NDIM + w*64 + it*16 + g*4 + r;
      #pragma unroll
      for (int ct = 0; ct < 2; ++ct) {
        const int col = h*DHD + ct*16 + m;
        const float gv = (float)gateb[(size_t)row*DCC + col];
        zcom[(size_t)row*DCC + col] = (f16)(o[it][ct][r] * rr * gv);
      }
    }
}

// ---------------- K3: output projection via MFMA ----------------
// 128 rows/block, wave = 32 rows. A = Wo^T frags (global), B = zcom frags (global).
// Lane holds out[row=m][4 consecutive cols] -> float4 stores.
__global__ __launch_bounds__(256, 2) void k3_out(
    const f16* __restrict__ zcom, const f16* __restrict__ wo16,
    const float* __restrict__ bo, float* __restrict__ out)
{
  const int t = threadIdx.x;
  const int w = t >> 6, lane = t & 63;
  const int m = lane & 15, g = lane >> 4;
  const int row0 = blockIdx.x * 128 + w * 32;

  f32x4 acc[2][8];
  #pragma unroll
  for (int it=0;it<2;++it)
    #pragma unroll
    for (int jt=0;jt<8;++jt) acc[it][jt] = (f32x4){0.f,0.f,0.f,0.f};

  #pragma unroll
  for (int ks = 0; ks < 4; ++ks) {
    f16x8 af[8];
    #pragma unroll
    for (int jt=0;jt<8;++jt)
      af[jt] = *reinterpret_cast<const f16x8*>(wo16 + (jt*16+m)*128 + ks*32 + g*8);
    f16x8 bf[2];
    #pragma unroll
    for (int it=0;it<2;++it)
      bf[it] = *reinterpret_cast<const f16x8*>(zcom + (size_t)(row0 + it*16 + m)*DCC + ks*32 + g*8);
    #pragma unroll
    for (int it=0;it<2;++it)
      #pragma unroll
      for (int jt=0;jt<8;++jt)
        acc[it][jt] = __builtin_amdgcn_mfma_f32_16x16x32_f16(af[jt], bf[it], acc[it][jt], 0,0,0);
  }

  float4 bias[8];
  #pragma unroll
  for (int jt=0;jt<8;++jt)
    bias[jt] = *reinterpret_cast<const float4*>(bo + jt*16 + g*4);

  #pragma unroll
  for (int it=0;it<2;++it) {
    const size_t row = row0 + it*16 + m;
    #pragma unroll
    for (int jt=0;jt<8;++jt) {
      float4 o;
      o.x = acc[it][jt][0] + bias[jt].x;
      o.y = acc[it][jt][1] + bias[jt].y;
      o.z = acc[it][jt][2] + bias[jt].z;
      o.w = acc[it][jt][3] + bias[jt].w;
      *reinterpret_cast<float4*>(out + row*DZC + jt*16 + g*4) = o;
    }
  }
}

extern "C" void kernel_launch(void* const* d_in, const int* in_sizes, int n_in,
                              void* d_out, int out_size, void* d_ws, size_t ws_size,
                              hipStream_t stream) {
  const float* z    = (const float*)d_in[0];
  const float* dist = (const float*)d_in[1];
  const float* lng  = (const float*)d_in[2];
  const float* lnb  = (const float*)d_in[3];
  const float* Wq   = (const float*)d_in[4];
  const float* bq   = (const float*)d_in[5];
  const float* Wk   = (const float*)d_in[6];
  const float* bk   = (const float*)d_in[7];
  const float* Wv   = (const float*)d_in[8];
  const float* bv   = (const float*)d_in[9];
  const float* Wg   = (const float*)d_in[10];
  const float* bg   = (const float*)d_in[11];
  const float* Wo   = (const float*)d_in[12];
  const float* bo   = (const float*)d_in[13];
  float* out = (float*)d_out;

  const size_t elems = (size_t)MROWS * DCC;  // 8,388,608
  f16* qb    = (f16*)d_ws;
  f16* kbuf  = qb    + elems;
  f16* vbuf  = kbuf  + elems;
  f16* gateb = vbuf  + elems;
  f16* zcom  = gateb + elems;
  f16* coefp = zcom  + elems;            // 16,777,216 halves
  f16* w16   = coefp + (size_t)LDIM*NDIM*NDIM;  // 5*16384 halves; ws ≈ 117.6 MB

  k0b_pack<<<320, 256, 0, stream>>>(Wq, Wk, Wv, Wg, Wo, w16);
  k0_coef<<<(LDIM*NDIM*NDIM)/(256*8), 256, 0, stream>>>(dist, coefp);
  k1_ln_qkvg<<<MROWS/64, 256, 0, stream>>>(z, lng, lnb, w16, bq, bk, bv, bg,
                                           qb, kbuf, vbuf, gateb);
  k2_attn<<<LDIM*HN, 256, 0, stream>>>(qb, kbuf, vbuf, gateb, coefp, zcom);
  k3_out<<<MROWS/128, 256, 0, stream>>>(zcom, w16 + 4*16384, bo, out);
}